// Round 6
// baseline (5973.582 us; speedup 1.0000x reference)
//
#include <hip/hip_runtime.h>
#include <hip/hip_bf16.h>

#define NN 100000
#define NE 400000
#define NG 1000

typedef __attribute__((ext_vector_type(8))) short bf16x8;
typedef __attribute__((ext_vector_type(4))) float f32x4;

// ---------------- bf16 <-> f32 helpers (bit-level, RNE) ----------------
__device__ __forceinline__ float bf2f(unsigned short h) {
    return __uint_as_float((unsigned)h << 16);
}
__device__ __forceinline__ unsigned short f2bf(float f) {
    unsigned u = __float_as_uint(f);
    return (unsigned short)((u + 0x7FFFu + ((u >> 16) & 1u)) >> 16);
}
__device__ __forceinline__ void up8(uint4 u, float v[8]) {
    v[0] = bf2f((unsigned short)u.x); v[1] = bf2f((unsigned short)(u.x >> 16));
    v[2] = bf2f((unsigned short)u.y); v[3] = bf2f((unsigned short)(u.y >> 16));
    v[4] = bf2f((unsigned short)u.z); v[5] = bf2f((unsigned short)(u.z >> 16));
    v[6] = bf2f((unsigned short)u.w); v[7] = bf2f((unsigned short)(u.w >> 16));
}
__device__ __forceinline__ uint4 pk8(const float v[8]) {
    uint4 r;
    r.x = (uint)f2bf(v[0]) | ((uint)f2bf(v[1]) << 16);
    r.y = (uint)f2bf(v[2]) | ((uint)f2bf(v[3]) << 16);
    r.z = (uint)f2bf(v[4]) | ((uint)f2bf(v[5]) << 16);
    r.w = (uint)f2bf(v[6]) | ((uint)f2bf(v[7]) << 16);
    return r;
}

// ---------------- diagnostic fallback ----------------
__global__ void diag_kernel(float* __restrict__ out, int n, float val) {
    int i = blockIdx.x * 256 + threadIdx.x;
    if (i < n) out[i] = val;
}

// ---------------- degree / invdeg ----------------
__global__ void deg_kernel(const int* __restrict__ dst, int* __restrict__ deg) {
    int e = blockIdx.x * 256 + threadIdx.x;
    if (e < NE) atomicAdd(&deg[dst[e]], 1);
}

__global__ void invdeg_kernel(const int* __restrict__ deg, float* __restrict__ invdeg) {
    int n = blockIdx.x * 256 + threadIdx.x;
    if (n < NN) invdeg[n] = 1.0f / (float)(deg[n] > 0 ? deg[n] : 1);
}

// ---------------- conv1 node-level first linear (K=5), bf16 out ----------------
__global__ void conv1_node_kernel(const float* __restrict__ x, const float* __restrict__ W,
                                  unsigned short* __restrict__ RQ) {
    __shared__ float Ws[1280];  // [10][128]
    for (int i = threadIdx.x; i < 1280; i += 256) Ws[i] = W[i];
    __syncthreads();
    int c = threadIdx.x & 127;
    int which = threadIdx.x >> 7;
    for (int n = blockIdx.x; n < NN; n += gridDim.x) {
        float acc = 0.f;
        #pragma unroll
        for (int r = 0; r < 5; r++) {
            float xv = x[n * 5 + r];
            float bot = Ws[(5 + r) * 128 + c];
            float w = which ? bot : (Ws[r * 128 + c] - bot);
            acc = fmaf(xv, w, acc);
        }
        RQ[(size_t)n * 256 + threadIdx.x] = f2bf(acc);
    }
}

// ---------------- weight transpose+convert: Wt[N][K] bf16 from W[K][N] f32 ----------------
__global__ void wtrans_kernel(const float* __restrict__ W, unsigned short* __restrict__ Wt,
                              int K, int N) {
    int idx = blockIdx.x * 256 + threadIdx.x;
    if (idx >= K * N) return;
    int c = idx / K, k = idx - c * K;
    Wt[(size_t)c * K + k] = f2bf(W[(size_t)k * N + c]);
}

// ---------------- wprime transposed bf16: Wpt[2C][K] from W[2K][C] ----------------
__global__ void wprime_t_kernel(const float* __restrict__ W, unsigned short* __restrict__ Wpt,
                                int K, int C) {
    int idx = blockIdx.x * 256 + threadIdx.x;
    if (idx >= 2 * C * K) return;
    int n = idx / K, k = idx - n * K;
    float v;
    if (n < C) v = W[(size_t)k * C + n] - W[(size_t)(K + k) * C + n];
    else       v = W[(size_t)(K + k) * C + (n - C)];
    Wpt[(size_t)n * K + k] = f2bf(v);
}

// ---------------- gather-stats (vectorized, NO store) ----------------
template<int C>
__global__ void gstats_kernel(const unsigned short* __restrict__ RQ, const int* __restrict__ src,
                              const int* __restrict__ dst, const float* __restrict__ bias,
                              float* __restrict__ ssum, float* __restrict__ ssq) {
    constexpr int LPE = C / 8;        // lanes per edge
    constexpr int EPB = 256 / LPE;    // edges per block-iter
    const int t = threadIdx.x;
    const int le = t % LPE, sub = t / LPE;
    const int c0 = le * 8;
    float4 b0 = *(const float4*)&bias[c0];
    float4 b1 = *(const float4*)&bias[c0 + 4];
    float bb[8] = {b0.x, b0.y, b0.z, b0.w, b1.x, b1.y, b1.z, b1.w};
    float ls[8], lq[8];
    #pragma unroll
    for (int i = 0; i < 8; i++) { ls[i] = 0.f; lq[i] = 0.f; }
    for (int e = blockIdx.x * EPB + sub; e < NE; e += gridDim.x * EPB) {
        int d = dst[e], s = src[e];
        uint4 rr = *(const uint4*)&RQ[(size_t)d * (2 * C) + c0];
        uint4 qq = *(const uint4*)&RQ[(size_t)s * (2 * C) + C + c0];
        float pr[8], pq[8];
        up8(rr, pr); up8(qq, pq);
        #pragma unroll
        for (int i = 0; i < 8; i++) {
            float v = pr[i] + pq[i] + bb[i];
            ls[i] += v; lq[i] += v * v;
        }
    }
    __shared__ float red[2][256][8];
    #pragma unroll
    for (int i = 0; i < 8; i++) { red[0][t][i] = ls[i]; red[1][t][i] = lq[i]; }
    __syncthreads();
    if (t < C) {
        int le2 = t >> 3, ch = t & 7;
        float s = 0.f, q = 0.f;
        #pragma unroll
        for (int g = 0; g < EPB; g++) {
            s += red[0][g * LPE + le2][ch];
            q += red[1][g * LPE + le2][ch];
        }
        atomicAdd(&ssum[t], s);
        atomicAdd(&ssq[t], q);
    }
}

// ---------------- GraphNorm stats -> per-channel affine ----------------
__global__ void finalize_kernel(const float* __restrict__ ssum, const float* __restrict__ ssq,
                                const float* __restrict__ gn, int C, float invM,
                                float* __restrict__ alpha, float* __restrict__ beta) {
    int c = threadIdx.x;
    if (c >= C) return;
    float g = gn[c], b = gn[C + c], ms = gn[2 * C + c];
    float m = ssum[c] * invM;
    float var = ssq[c] * invM - m * m * ms * (2.f - ms);
    float inv = rsqrtf(var + 1e-5f);
    alpha[c] = g * inv;
    beta[c] = b - g * inv * ms * m;
}

// ================= MFMA GEMM v2: pipelined, B direct-from-global =================
// Block: 256 thr (4 waves), tile 64 x BN, BK=32. One barrier per K-step (dbuf A).
// GATHER: A-row e = RQ[dst[e]][0:K]+RQ[src[e]][K:2K]+biasIn (bf16, M%64==0)
// NORMRELU: relu(alpha*a+beta); ROWSC: a*rowscale[row] (AF32 input)
// STATS: colwise sum/sumsq of (acc+biasOut) -> atomics [M%64==0]
// STORE: bf16 C (row-guarded); SCAT: relu(alphaO*o+betaO) scattered to hsum[dst] [M%64==0]
template<int BN, bool GATHER, bool NORMRELU, bool ROWSC, bool STATS, bool STORE, bool SCAT,
         bool AF32>
__global__ __launch_bounds__(256) void mgemm_kernel(
    const void* __restrict__ Av, const int* __restrict__ gsrc, const int* __restrict__ gdst,
    const float* __restrict__ biasIn, const unsigned short* __restrict__ Wt,
    const float* __restrict__ alpha, const float* __restrict__ beta,
    const float* __restrict__ rowscale, const float* __restrict__ biasOut,
    unsigned short* __restrict__ Cmat, int M, int K, int N,
    float* __restrict__ ssum, float* __restrict__ ssq,
    const float* __restrict__ alphaO, const float* __restrict__ betaO,
    float* __restrict__ hsum) {
    constexpr int WNC = BN / 4;
    constexpr int NF = WNC / 16;
    __shared__ __align__(16) unsigned short At[2][64][40];
    __shared__ __align__(16) float sAl[256], sBe[256], sBi[256];
    __shared__ float sS[BN], sQ[BN];
    const int t = threadIdx.x;
    const int wave = t >> 6, lane = t & 63;
    const int l15 = lane & 15, lq = lane >> 4;
    const int r0 = blockIdx.y * 64;
    const int n0 = blockIdx.x * BN;
    const int srow = t >> 2, skq = t & 3;

    if (NORMRELU) for (int i = t; i < K; i += 256) { sAl[i] = alpha[i]; sBe[i] = beta[i]; }
    if (GATHER)   for (int i = t; i < K; i += 256) { sBi[i] = biasIn[i]; }
    if (STATS && t < BN) { sS[t] = 0.f; sQ[t] = 0.f; }

    const int ar = r0 + srow;
    int gd = 0, gs = 0;
    if (GATHER) { gd = gdst[ar]; gs = gsrc[ar]; }
    float rs = 1.f;
    if (ROWSC) rs = (ar < M) ? rowscale[ar] : 0.f;

    const unsigned short* Abf = (const unsigned short*)Av;
    const float* Af = (const float*)Av;

    const unsigned short* bp[NF];
    #pragma unroll
    for (int cf = 0; cf < NF; cf++)
        bp[cf] = &Wt[(size_t)(n0 + wave * WNC + 16 * cf + l15) * K + lq * 8];

    f32x4 acc[4][NF];
    #pragma unroll
    for (int i = 0; i < 4; i++)
        #pragma unroll
        for (int j = 0; j < NF; j++) acc[i][j] = {0.f, 0.f, 0.f, 0.f};

    uint4 rA, rQ;
    float4 fA0, fA1;
    auto loadRaw = [&](int k0, uint4& a, uint4& q, float4& f0, float4& f1) {
        int kb = k0 + skq * 8;
        if (GATHER) {
            a = *(const uint4*)&Abf[(size_t)gd * (2 * K) + kb];
            q = *(const uint4*)&Abf[(size_t)gs * (2 * K) + K + kb];
        } else if (AF32) {
            if (ar < M) {
                f0 = *(const float4*)&Af[(size_t)ar * K + kb];
                f1 = *(const float4*)&Af[(size_t)ar * K + kb + 4];
            } else { f0 = make_float4(0, 0, 0, 0); f1 = f0; }
        } else {
            if (ar < M) a = *(const uint4*)&Abf[(size_t)ar * K + kb];
            else a = make_uint4(0, 0, 0, 0);
        }
    };
    auto stage = [&](int k0, int buf, uint4 a, uint4 q, float4 f0, float4 f1) {
        int kb = k0 + skq * 8;
        float v[8];
        if (GATHER) {
            float pa[8], pq[8];
            up8(a, pa); up8(q, pq);
            float4 b0 = *(const float4*)&sBi[kb];
            float4 b1 = *(const float4*)&sBi[kb + 4];
            float bb[8] = {b0.x, b0.y, b0.z, b0.w, b1.x, b1.y, b1.z, b1.w};
            #pragma unroll
            for (int i = 0; i < 8; i++) v[i] = pa[i] + pq[i] + bb[i];
        } else if (AF32) {
            v[0] = f0.x; v[1] = f0.y; v[2] = f0.z; v[3] = f0.w;
            v[4] = f1.x; v[5] = f1.y; v[6] = f1.z; v[7] = f1.w;
        } else {
            up8(a, v);
        }
        if (NORMRELU) {
            float4 a0 = *(const float4*)&sAl[kb];
            float4 a1 = *(const float4*)&sAl[kb + 4];
            float4 e0 = *(const float4*)&sBe[kb];
            float4 e1 = *(const float4*)&sBe[kb + 4];
            float al[8] = {a0.x, a0.y, a0.z, a0.w, a1.x, a1.y, a1.z, a1.w};
            float be[8] = {e0.x, e0.y, e0.z, e0.w, e1.x, e1.y, e1.z, e1.w};
            #pragma unroll
            for (int i = 0; i < 8; i++) v[i] = fmaxf(fmaf(al[i], v[i], be[i]), 0.f);
        }
        if (ROWSC) {
            #pragma unroll
            for (int i = 0; i < 8; i++) v[i] *= rs;
        }
        *(uint4*)&At[buf][srow][skq * 8] = pk8(v);
    };

    // prologue: issue first loads, fill tables, stage tile 0
    loadRaw(0, rA, rQ, fA0, fA1);
    bf16x8 bcur[NF];
    #pragma unroll
    for (int cf = 0; cf < NF; cf++) bcur[cf] = *(const bf16x8*)(bp[cf] + 0);
    __syncthreads();  // tables (sAl/sBe/sBi) ready
    stage(0, 0, rA, rQ, fA0, fA1);
    __syncthreads();  // At[0] ready

    int buf = 0;
    for (int k0 = 0; k0 < K; k0 += 32) {
        int nxt = k0 + 32;
        uint4 nA, nQ;
        float4 nf0, nf1;
        bf16x8 bnxt[NF];
        if (nxt < K) {
            loadRaw(nxt, nA, nQ, nf0, nf1);
            #pragma unroll
            for (int cf = 0; cf < NF; cf++) bnxt[cf] = *(const bf16x8*)(bp[cf] + nxt);
        }
        bf16x8 af[4];
        #pragma unroll
        for (int rf = 0; rf < 4; rf++)
            af[rf] = *(const bf16x8*)&At[buf][16 * rf + l15][lq * 8];
        #pragma unroll
        for (int rf = 0; rf < 4; rf++)
            #pragma unroll
            for (int cf = 0; cf < NF; cf++)
                acc[rf][cf] = __builtin_amdgcn_mfma_f32_16x16x32_bf16(
                    af[rf], bcur[cf], acc[rf][cf], 0, 0, 0);
        if (nxt < K) {
            stage(nxt, buf ^ 1, nA, nQ, nf0, nf1);
            __syncthreads();
            buf ^= 1;
            #pragma unroll
            for (int cf = 0; cf < NF; cf++) bcur[cf] = bnxt[cf];
        }
    }

    // ---------------- epilogue ----------------
    int cA[NF];
    float bO[NF], aO[NF], bOo[NF];
    #pragma unroll
    for (int cf = 0; cf < NF; cf++) {
        cA[cf] = n0 + wave * WNC + 16 * cf + l15;
        bO[cf] = (biasOut != nullptr) ? biasOut[cA[cf]] : 0.f;
        if (SCAT) { aO[cf] = alphaO[cA[cf]]; bOo[cf] = betaO[cA[cf]]; }
    }
    float ps[NF], pq[NF];
    #pragma unroll
    for (int cf = 0; cf < NF; cf++) { ps[cf] = 0.f; pq[cf] = 0.f; }
    #pragma unroll
    for (int rf = 0; rf < 4; rf++) {
        int rb = r0 + 16 * rf + lq * 4;
        int dd[4];
        if (SCAT) {
            #pragma unroll
            for (int jj = 0; jj < 4; jj++) dd[jj] = gdst[rb + jj];
        }
        #pragma unroll
        for (int cf = 0; cf < NF; cf++) {
            #pragma unroll
            for (int jj = 0; jj < 4; jj++) {
                float o = acc[rf][cf][jj] + bO[cf];
                if (STATS) { ps[cf] += o; pq[cf] += o * o; }
                if (STORE) {
                    int r = rb + jj;
                    if (r < M) Cmat[(size_t)r * N + cA[cf]] = f2bf(o);
                }
                if (SCAT) {
                    float h = fmaxf(fmaf(aO[cf], o, bOo[cf]), 0.f);
                    atomicAdd(&hsum[(size_t)dd[jj] * N + cA[cf]], h);
                }
            }
        }
    }
    if (STATS) {
        #pragma unroll
        for (int cf = 0; cf < NF; cf++) {
            float s = ps[cf], q = pq[cf];
            s += __shfl_xor(s, 16); s += __shfl_xor(s, 32);
            q += __shfl_xor(q, 16); q += __shfl_xor(q, 32);
            if (lq == 0) {
                atomicAdd(&sS[cA[cf] - n0], s);
                atomicAdd(&sQ[cA[cf] - n0], q);
            }
        }
        __syncthreads();
        if (t < BN) {
            atomicAdd(&ssum[n0 + t], sS[t]);
            atomicAdd(&ssq[n0 + t], sQ[t]);
        }
    }
}

// ---------------- norm+relu a bf16 Y, scatter-add (vectorized) ----------------
template<int C>
__global__ void aggregate_kernel(const unsigned short* __restrict__ Y, const int* __restrict__ dst,
                                 const float* __restrict__ alpha, const float* __restrict__ beta,
                                 float* __restrict__ hsum) {
    constexpr int LPE = C / 8;
    constexpr int EPB = 256 / LPE;
    const int t = threadIdx.x;
    const int le = t % LPE, sub = t / LPE;
    const int c0 = le * 8;
    float4 a0 = *(const float4*)&alpha[c0];
    float4 a1 = *(const float4*)&alpha[c0 + 4];
    float4 e0 = *(const float4*)&beta[c0];
    float4 e1 = *(const float4*)&beta[c0 + 4];
    float al[8] = {a0.x, a0.y, a0.z, a0.w, a1.x, a1.y, a1.z, a1.w};
    float be[8] = {e0.x, e0.y, e0.z, e0.w, e1.x, e1.y, e1.z, e1.w};
    for (int e = blockIdx.x * EPB + sub; e < NE; e += gridDim.x * EPB) {
        int d = dst[e];
        uint4 yy = *(const uint4*)&Y[(size_t)e * C + c0];
        float v[8];
        up8(yy, v);
        #pragma unroll
        for (int i = 0; i < 8; i++) {
            float h = fmaxf(fmaf(al[i], v[i], be[i]), 0.f);
            atomicAdd(&hsum[(size_t)d * C + c0 + i], h);
        }
    }
}

// ---------------- conv3: fused gather+norm+relu+scatter (C=256, vectorized) ----------------
__global__ void aggregate_fg_kernel(const unsigned short* __restrict__ RQ,
                                    const int* __restrict__ src, const int* __restrict__ dst,
                                    const float* __restrict__ bias, const float* __restrict__ alpha,
                                    const float* __restrict__ beta, float* __restrict__ hsum) {
    const int t = threadIdx.x;
    const int le = t & 31, sub = t >> 5;  // 32 lanes/edge, 8 edges/block-iter
    const int c0 = le * 8;
    float4 a0 = *(const float4*)&alpha[c0];
    float4 a1 = *(const float4*)&alpha[c0 + 4];
    float4 e0 = *(const float4*)&beta[c0];
    float4 e1 = *(const float4*)&beta[c0 + 4];
    float4 b0 = *(const float4*)&bias[c0];
    float4 b1 = *(const float4*)&bias[c0 + 4];
    float al[8] = {a0.x, a0.y, a0.z, a0.w, a1.x, a1.y, a1.z, a1.w};
    float be[8] = {e0.x, e0.y, e0.z, e0.w, e1.x, e1.y, e1.z, e1.w};
    float bb[8] = {b0.x, b0.y, b0.z, b0.w, b1.x, b1.y, b1.z, b1.w};
    for (int e = blockIdx.x * 8 + sub; e < NE; e += gridDim.x * 8) {
        int d = dst[e], s = src[e];
        uint4 rr = *(const uint4*)&RQ[(size_t)d * 512 + c0];
        uint4 qq = *(const uint4*)&RQ[(size_t)s * 512 + 256 + c0];
        float pr[8], pq[8];
        up8(rr, pr); up8(qq, pq);
        #pragma unroll
        for (int i = 0; i < 8; i++) {
            float h = fmaxf(fmaf(al[i], pr[i] + pq[i] + bb[i], be[i]), 0.f);
            atomicAdd(&hsum[(size_t)d * 256 + c0 + i], h);
        }
    }
}

// ---------------- graph mean pool: contiguous chunks, run-local accumulation ----------------
__global__ void pool_kernel(const float* __restrict__ h3sum, const float* __restrict__ invdeg,
                            const int* __restrict__ batch, float* __restrict__ gsum,
                            int* __restrict__ gcnt) {
    int chunk = (NN + gridDim.x - 1) / gridDim.x;
    int nbeg = blockIdx.x * chunk;
    int nend = min(nbeg + chunk, NN);
    if (nbeg >= nend) return;
    int t = threadIdx.x;  // 256 = channel
    int curg = batch[nbeg];
    float acc = 0.f;
    int cnt = 0;
    for (int n = nbeg; n < nend; n++) {
        int g = batch[n];
        if (g != curg) {
            atomicAdd(&gsum[(size_t)curg * 256 + t], acc);
            if (t == 0) atomicAdd(&gcnt[curg], cnt);
            curg = g; acc = 0.f; cnt = 0;
        }
        acc += h3sum[(size_t)n * 256 + t] * invdeg[n];
        cnt++;
    }
    atomicAdd(&gsum[(size_t)curg * 256 + t], acc);
    if (t == 0) atomicAdd(&gcnt[curg], cnt);
}

// ---------------- final graph MLP ----------------
__global__ void mlp_kernel(const float* __restrict__ gsum, const int* __restrict__ gcnt,
                           const float* __restrict__ W1, const float* __restrict__ b1,
                           const float* __restrict__ W2, const float* __restrict__ b2,
                           float* __restrict__ out) {
    int g = blockIdx.x;
    int t = threadIdx.x;  // 256
    __shared__ float grow[256];
    __shared__ float r0s[256], r1s[256];
    int cnt = gcnt[g];
    float inv = 1.0f / (float)(cnt > 0 ? cnt : 1);
    grow[t] = gsum[(size_t)g * 256 + t] * inv;
    __syncthreads();
    float acc = b1[t];
    for (int k = 0; k < 256; k++) acc = fmaf(grow[k], W1[k * 256 + t], acc);
    float h = fmaxf(acc, 0.f);
    r0s[t] = h * W2[t * 2 + 0];
    r1s[t] = h * W2[t * 2 + 1];
    __syncthreads();
    for (int s = 128; s > 0; s >>= 1) {
        if (t < s) { r0s[t] += r0s[t + s]; r1s[t] += r1s[t + s]; }
        __syncthreads();
    }
    if (t == 0) {
        out[g * 2 + 0] = r0s[0] + b2[0];
        out[g * 2 + 1] = r1s[0] + b2[1];
    }
}

extern "C" void kernel_launch(void* const* d_in, const int* in_sizes, int n_in,
                              void* d_out, int out_size, void* d_ws, size_t ws_size,
                              hipStream_t stream) {
    const float* x      = (const float*)d_in[0];
    const int*   ei     = (const int*)d_in[1];
    const int*   src    = ei;
    const int*   dstp   = ei + NE;
    const int*   batch  = (const int*)d_in[2];
    const float* c1_w1  = (const float*)d_in[3];
    const float* c1_b1  = (const float*)d_in[4];
    const float* c1_gn1 = (const float*)d_in[5];
    const float* c1_w2  = (const float*)d_in[6];
    const float* c1_b2  = (const float*)d_in[7];
    const float* c1_gn2 = (const float*)d_in[8];
    const float* c1_w3  = (const float*)d_in[9];
    const float* c1_b3  = (const float*)d_in[10];
    const float* c1_gn3 = (const float*)d_in[11];
    const float* c2_w1  = (const float*)d_in[12];
    const float* c2_b1  = (const float*)d_in[13];
    const float* c2_gn1 = (const float*)d_in[14];
    const float* c2_w2  = (const float*)d_in[15];
    const float* c2_b2  = (const float*)d_in[16];
    const float* c2_gn2 = (const float*)d_in[17];
    const float* c3_w1  = (const float*)d_in[18];
    const float* c3_b1  = (const float*)d_in[19];
    const float* c3_gn1 = (const float*)d_in[20];
    const float* lin_w1 = (const float*)d_in[21];
    const float* lin_b1 = (const float*)d_in[22];
    const float* lin_w2 = (const float*)d_in[23];
    const float* lin_b2 = (const float*)d_in[24];
    float* out = (float*)d_out;

    // ======== workspace: ping-pong regions RA / RB (102.4 MB each) + tail ========
    //   RA: RQ1[NN,256]bf16 -> Y1c[NE,128]bf16 -> RQ2[NN,512]bf16 -> RQ3[NN,512]bf16
    //   RB: Y1b[NE,128]bf16 -> h1sum[NN,128]f32 -> h2sum[NN,256]f32 -> h3sum[NN,256]f32
    constexpr size_t REG_BYTES = (size_t)NE * 128 * 2;  // 102,400,000
    constexpr size_t NEED = 2 * REG_BYTES + 4 * 1024 * 1024;

    if (ws_size < NEED) {
        diag_kernel<<<(out_size + 255) / 256, 256, 0, stream>>>(
            out, out_size, (float)(ws_size >> 20));
        return;
    }

    char* base = (char*)d_ws;
    unsigned short* RA = (unsigned short*)base;
    unsigned short* RB = (unsigned short*)(base + REG_BYTES);
    float* h1sum = (float*)RB;
    float* h2sum = (float*)RB;
    float* h3sum = (float*)RB;
    char* p = base + 2 * REG_BYTES;
    auto alloc = [&](size_t bytes) -> void* {
        void* r = (void*)p;
        p += (bytes + 255) & ~(size_t)255;
        return r;
    };
    unsigned short* c1w2t = (unsigned short*)alloc((size_t)128 * 128 * 2);
    unsigned short* c1w3t = (unsigned short*)alloc((size_t)128 * 128 * 2);
    unsigned short* c2w2t = (unsigned short*)alloc((size_t)256 * 256 * 2);
    unsigned short* Wpt   = (unsigned short*)alloc((size_t)512 * 256 * 2);
    int*   deg    = (int*)alloc((size_t)NN * 4);
    float* invdeg = (float*)alloc((size_t)NN * 4);
    float* ssum   = (float*)alloc(256 * 4);
    float* ssq    = (float*)alloc(256 * 4);
    float* al0    = (float*)alloc(256 * 4);
    float* be0    = (float*)alloc(256 * 4);
    float* al1    = (float*)alloc(256 * 4);
    float* be1    = (float*)alloc(256 * 4);
    float* gsum   = (float*)alloc((size_t)NG * 256 * 4);
    int*   gcnt   = (int*)alloc((size_t)NG * 4);

    const float invE = 1.0f / (float)NE;
    const int MT_E = NE / 64;
    const int MT_N = (NN + 63) / 64;

    hipMemsetAsync(deg, 0, (size_t)NN * 4, stream);
    hipMemsetAsync(gsum, 0, (size_t)NG * 256 * 4, stream);
    hipMemsetAsync(gcnt, 0, (size_t)NG * 4, stream);

    deg_kernel<<<(NE + 255) / 256, 256, 0, stream>>>(dstp, deg);
    invdeg_kernel<<<(NN + 255) / 256, 256, 0, stream>>>(deg, invdeg);

    wtrans_kernel<<<(128 * 128 + 255) / 256, 256, 0, stream>>>(c1_w2, c1w2t, 128, 128);
    wtrans_kernel<<<(128 * 128 + 255) / 256, 256, 0, stream>>>(c1_w3, c1w3t, 128, 128);
    wtrans_kernel<<<(256 * 256 + 255) / 256, 256, 0, stream>>>(c2_w2, c2w2t, 256, 256);

    // ================= conv1 =================
    conv1_node_kernel<<<2048, 256, 0, stream>>>(x, c1_w1, RA);
    hipMemsetAsync(ssum, 0, 256 * 4, stream);
    hipMemsetAsync(ssq, 0, 256 * 4, stream);
    gstats_kernel<128><<<2048, 256, 0, stream>>>(RA, src, dstp, c1_b1, ssum, ssq);
    finalize_kernel<<<1, 256, 0, stream>>>(ssum, ssq, c1_gn1, 128, invE, al0, be0);

    hipMemsetAsync(ssum, 0, 256 * 4, stream);
    hipMemsetAsync(ssq, 0, 256 * 4, stream);
    mgemm_kernel<128, true, true, false, true, true, false, false>
        <<<dim3(1, MT_E), 256, 0, stream>>>(RA, src, dstp, c1_b1, c1w2t, al0, be0,
                                            nullptr, c1_b2, RB, NE, 128, 128,
                                            ssum, ssq, nullptr, nullptr, nullptr);
    finalize_kernel<<<1, 256, 0, stream>>>(ssum, ssq, c1_gn2, 128, invE, al0, be0);

    hipMemsetAsync(ssum, 0, 256 * 4, stream);
    hipMemsetAsync(ssq, 0, 256 * 4, stream);
    mgemm_kernel<128, false, true, false, true, true, false, false>
        <<<dim3(1, MT_E), 256, 0, stream>>>(RB, nullptr, nullptr, nullptr, c1w3t, al0, be0,
                                            nullptr, c1_b3, RA, NE, 128, 128,
                                            ssum, ssq, nullptr, nullptr, nullptr);
    finalize_kernel<<<1, 256, 0, stream>>>(ssum, ssq, c1_gn3, 128, invE, al0, be0);

    hipMemsetAsync(h1sum, 0, (size_t)NN * 128 * 4, stream);
    aggregate_kernel<128><<<2048, 256, 0, stream>>>(RA, dstp, al0, be0, h1sum);

    // ================= conv2 =================
    wprime_t_kernel<<<(512 * 128 + 255) / 256, 256, 0, stream>>>(c2_w1, Wpt, 128, 256);
    mgemm_kernel<256, false, false, true, false, true, false, true>
        <<<dim3(2, MT_N), 256, 0, stream>>>(h1sum, nullptr, nullptr, nullptr, Wpt,
                                            nullptr, nullptr, invdeg, nullptr, RA,
                                            NN, 128, 512, nullptr, nullptr,
                                            nullptr, nullptr, nullptr);
    hipMemsetAsync(ssum, 0, 256 * 4, stream);
    hipMemsetAsync(ssq, 0, 256 * 4, stream);
    gstats_kernel<256><<<2048, 256, 0, stream>>>(RA, src, dstp, c2_b1, ssum, ssq);
    finalize_kernel<<<1, 256, 0, stream>>>(ssum, ssq, c2_gn1, 256, invE, al0, be0);

    hipMemsetAsync(ssum, 0, 256 * 4, stream);
    hipMemsetAsync(ssq, 0, 256 * 4, stream);
    mgemm_kernel<256, true, true, false, true, false, false, false>
        <<<dim3(1, MT_E), 256, 0, stream>>>(RA, src, dstp, c2_b1, c2w2t, al0, be0,
                                            nullptr, c2_b2, nullptr, NE, 256, 256,
                                            ssum, ssq, nullptr, nullptr, nullptr);
    finalize_kernel<<<1, 256, 0, stream>>>(ssum, ssq, c2_gn2, 256, invE, al1, be1);

    hipMemsetAsync(h2sum, 0, (size_t)NN * 256 * 4, stream);
    mgemm_kernel<256, true, true, false, false, false, true, false>
        <<<dim3(1, MT_E), 256, 0, stream>>>(RA, src, dstp, c2_b1, c2w2t, al0, be0,
                                            nullptr, c2_b2, nullptr, NE, 256, 256,
                                            nullptr, nullptr, al1, be1, h2sum);

    // ================= conv3 =================
    wprime_t_kernel<<<(512 * 256 + 255) / 256, 256, 0, stream>>>(c3_w1, Wpt, 256, 256);
    mgemm_kernel<256, false, false, true, false, true, false, true>
        <<<dim3(2, MT_N), 256, 0, stream>>>(h2sum, nullptr, nullptr, nullptr, Wpt,
                                            nullptr, nullptr, invdeg, nullptr, RA,
                                            NN, 256, 512, nullptr, nullptr,
                                            nullptr, nullptr, nullptr);
    hipMemsetAsync(ssum, 0, 256 * 4, stream);
    hipMemsetAsync(ssq, 0, 256 * 4, stream);
    gstats_kernel<256><<<2048, 256, 0, stream>>>(RA, src, dstp, c3_b1, ssum, ssq);
    finalize_kernel<<<1, 256, 0, stream>>>(ssum, ssq, c3_gn1, 256, invE, al0, be0);

    hipMemsetAsync(h3sum, 0, (size_t)NN * 256 * 4, stream);
    aggregate_fg_kernel<<<2048, 256, 0, stream>>>(RA, src, dstp, c3_b1, al0, be0, h3sum);

    // ================= pool + MLP =================
    pool_kernel<<<512, 256, 0, stream>>>(h3sum, invdeg, batch, gsum, gcnt);
    mlp_kernel<<<NG, 256, 0, stream>>>(gsum, gcnt, lin_w1, lin_b1, lin_w2, lin_b2, out);
}

// Round 7
// 2285.718 us; speedup vs baseline: 2.6134x; 2.6134x over previous
//
#include <hip/hip_runtime.h>
#include <hip/hip_bf16.h>

#define NN 100000
#define NE 400000
#define NG 1000

typedef __attribute__((ext_vector_type(8))) short bf16x8;
typedef __attribute__((ext_vector_type(4))) float f32x4;

// ---------------- bf16 <-> f32 helpers (bit-level, RNE) ----------------
__device__ __forceinline__ float bf2f(unsigned short h) {
    return __uint_as_float((unsigned)h << 16);
}
__device__ __forceinline__ unsigned short f2bf(float f) {
    unsigned u = __float_as_uint(f);
    return (unsigned short)((u + 0x7FFFu + ((u >> 16) & 1u)) >> 16);
}
__device__ __forceinline__ void up8(uint4 u, float v[8]) {
    v[0] = bf2f((unsigned short)u.x); v[1] = bf2f((unsigned short)(u.x >> 16));
    v[2] = bf2f((unsigned short)u.y); v[3] = bf2f((unsigned short)(u.y >> 16));
    v[4] = bf2f((unsigned short)u.z); v[5] = bf2f((unsigned short)(u.z >> 16));
    v[6] = bf2f((unsigned short)u.w); v[7] = bf2f((unsigned short)(u.w >> 16));
}
__device__ __forceinline__ uint4 pk8(const float v[8]) {
    uint4 r;
    r.x = (uint)f2bf(v[0]) | ((uint)f2bf(v[1]) << 16);
    r.y = (uint)f2bf(v[2]) | ((uint)f2bf(v[3]) << 16);
    r.z = (uint)f2bf(v[4]) | ((uint)f2bf(v[5]) << 16);
    r.w = (uint)f2bf(v[6]) | ((uint)f2bf(v[7]) << 16);
    return r;
}

// ---------------- diagnostic fallback ----------------
__global__ void diag_kernel(float* __restrict__ out, int n, float val) {
    int i = blockIdx.x * 256 + threadIdx.x;
    if (i < n) out[i] = val;
}

// ---------------- degree / invdeg ----------------
__global__ void deg_kernel(const int* __restrict__ dst, int* __restrict__ deg) {
    int e = blockIdx.x * 256 + threadIdx.x;
    if (e < NE) atomicAdd(&deg[dst[e]], 1);
}

__global__ void invdeg_kernel(const int* __restrict__ deg, float* __restrict__ invdeg) {
    int n = blockIdx.x * 256 + threadIdx.x;
    if (n < NN) invdeg[n] = 1.0f / (float)(deg[n] > 0 ? deg[n] : 1);
}

// ---------------- conv1 node-level first linear (K=5), bf16 out ----------------
__global__ void conv1_node_kernel(const float* __restrict__ x, const float* __restrict__ W,
                                  unsigned short* __restrict__ RQ) {
    __shared__ float Ws[1280];  // [10][128]
    for (int i = threadIdx.x; i < 1280; i += 256) Ws[i] = W[i];
    __syncthreads();
    int c = threadIdx.x & 127;
    int which = threadIdx.x >> 7;
    for (int n = blockIdx.x; n < NN; n += gridDim.x) {
        float acc = 0.f;
        #pragma unroll
        for (int r = 0; r < 5; r++) {
            float xv = x[n * 5 + r];
            float bot = Ws[(5 + r) * 128 + c];
            float w = which ? bot : (Ws[r * 128 + c] - bot);
            acc = fmaf(xv, w, acc);
        }
        RQ[(size_t)n * 256 + threadIdx.x] = f2bf(acc);
    }
}

// ---------------- weight transpose+convert: Wt[N][K] bf16 from W[K][N] f32 ----------------
__global__ void wtrans_kernel(const float* __restrict__ W, unsigned short* __restrict__ Wt,
                              int K, int N) {
    int idx = blockIdx.x * 256 + threadIdx.x;
    if (idx >= K * N) return;
    int c = idx / K, k = idx - c * K;
    Wt[(size_t)c * K + k] = f2bf(W[(size_t)k * N + c]);
}

// ---------------- wprime transposed bf16: Wpt[2C][K] from W[2K][C] ----------------
__global__ void wprime_t_kernel(const float* __restrict__ W, unsigned short* __restrict__ Wpt,
                                int K, int C) {
    int idx = blockIdx.x * 256 + threadIdx.x;
    if (idx >= 2 * C * K) return;
    int n = idx / K, k = idx - n * K;
    float v;
    if (n < C) v = W[(size_t)k * C + n] - W[(size_t)(K + k) * C + n];
    else       v = W[(size_t)(K + k) * C + (n - C)];
    Wpt[(size_t)n * K + k] = f2bf(v);
}

// ---------------- gather-stats (vectorized loads, NO store, LDS reduce) ----------------
template<int C>
__global__ void gstats_kernel(const unsigned short* __restrict__ RQ, const int* __restrict__ src,
                              const int* __restrict__ dst, const float* __restrict__ bias,
                              float* __restrict__ ssum, float* __restrict__ ssq) {
    constexpr int LPE = C / 8;        // lanes per edge
    constexpr int EPB = 256 / LPE;    // edges per block-iter
    const int t = threadIdx.x;
    const int le = t % LPE, sub = t / LPE;
    const int c0 = le * 8;
    float4 b0 = *(const float4*)&bias[c0];
    float4 b1 = *(const float4*)&bias[c0 + 4];
    float bb[8] = {b0.x, b0.y, b0.z, b0.w, b1.x, b1.y, b1.z, b1.w};
    float ls[8], lq[8];
    #pragma unroll
    for (int i = 0; i < 8; i++) { ls[i] = 0.f; lq[i] = 0.f; }
    for (int e = blockIdx.x * EPB + sub; e < NE; e += gridDim.x * EPB) {
        int d = dst[e], s = src[e];
        uint4 rr = *(const uint4*)&RQ[(size_t)d * (2 * C) + c0];
        uint4 qq = *(const uint4*)&RQ[(size_t)s * (2 * C) + C + c0];
        float pr[8], pq[8];
        up8(rr, pr); up8(qq, pq);
        #pragma unroll
        for (int i = 0; i < 8; i++) {
            float v = pr[i] + pq[i] + bb[i];
            ls[i] += v; lq[i] += v * v;
        }
    }
    __shared__ float red[2][256][8];
    #pragma unroll
    for (int i = 0; i < 8; i++) { red[0][t][i] = ls[i]; red[1][t][i] = lq[i]; }
    __syncthreads();
    if (t < C) {
        int le2 = t >> 3, ch = t & 7;
        float s = 0.f, q = 0.f;
        #pragma unroll
        for (int g = 0; g < EPB; g++) {
            s += red[0][g * LPE + le2][ch];
            q += red[1][g * LPE + le2][ch];
        }
        atomicAdd(&ssum[t], s);
        atomicAdd(&ssq[t], q);
    }
}

// ---------------- GraphNorm stats -> per-channel affine ----------------
__global__ void finalize_kernel(const float* __restrict__ ssum, const float* __restrict__ ssq,
                                const float* __restrict__ gn, int C, float invM,
                                float* __restrict__ alpha, float* __restrict__ beta) {
    int c = threadIdx.x;
    if (c >= C) return;
    float g = gn[c], b = gn[C + c], ms = gn[2 * C + c];
    float m = ssum[c] * invM;
    float var = ssq[c] * invM - m * m * ms * (2.f - ms);
    float inv = rsqrtf(var + 1e-5f);
    alpha[c] = g * inv;
    beta[c] = b - g * inv * ms * m;
}

// ================= MFMA GEMM v2: pipelined, B direct-from-global =================
// Block: 256 thr (4 waves), tile 64 x BN, BK=32. One barrier per K-step (dbuf A).
template<int BN, bool GATHER, bool NORMRELU, bool ROWSC, bool STATS, bool STORE, bool SCAT,
         bool AF32>
__global__ __launch_bounds__(256) void mgemm_kernel(
    const void* __restrict__ Av, const int* __restrict__ gsrc, const int* __restrict__ gdst,
    const float* __restrict__ biasIn, const unsigned short* __restrict__ Wt,
    const float* __restrict__ alpha, const float* __restrict__ beta,
    const float* __restrict__ rowscale, const float* __restrict__ biasOut,
    unsigned short* __restrict__ Cmat, int M, int K, int N,
    float* __restrict__ ssum, float* __restrict__ ssq,
    const float* __restrict__ alphaO, const float* __restrict__ betaO,
    float* __restrict__ hsum) {
    constexpr int WNC = BN / 4;
    constexpr int NF = WNC / 16;
    __shared__ __align__(16) unsigned short At[2][64][40];
    __shared__ __align__(16) float sAl[256], sBe[256], sBi[256];
    __shared__ float sS[BN], sQ[BN];
    const int t = threadIdx.x;
    const int wave = t >> 6, lane = t & 63;
    const int l15 = lane & 15, lq = lane >> 4;
    const int r0 = blockIdx.y * 64;
    const int n0 = blockIdx.x * BN;
    const int srow = t >> 2, skq = t & 3;

    if (NORMRELU) for (int i = t; i < K; i += 256) { sAl[i] = alpha[i]; sBe[i] = beta[i]; }
    if (GATHER)   for (int i = t; i < K; i += 256) { sBi[i] = biasIn[i]; }
    if (STATS && t < BN) { sS[t] = 0.f; sQ[t] = 0.f; }

    const int ar = r0 + srow;
    int gd = 0, gs = 0;
    if (GATHER) { gd = gdst[ar]; gs = gsrc[ar]; }
    float rs = 1.f;
    if (ROWSC) rs = (ar < M) ? rowscale[ar] : 0.f;

    const unsigned short* Abf = (const unsigned short*)Av;
    const float* Af = (const float*)Av;

    const unsigned short* bp[NF];
    #pragma unroll
    for (int cf = 0; cf < NF; cf++)
        bp[cf] = &Wt[(size_t)(n0 + wave * WNC + 16 * cf + l15) * K + lq * 8];

    f32x4 acc[4][NF];
    #pragma unroll
    for (int i = 0; i < 4; i++)
        #pragma unroll
        for (int j = 0; j < NF; j++) acc[i][j] = {0.f, 0.f, 0.f, 0.f};

    uint4 rA, rQ;
    float4 fA0, fA1;
    auto loadRaw = [&](int k0, uint4& a, uint4& q, float4& f0, float4& f1) {
        int kb = k0 + skq * 8;
        if (GATHER) {
            a = *(const uint4*)&Abf[(size_t)gd * (2 * K) + kb];
            q = *(const uint4*)&Abf[(size_t)gs * (2 * K) + K + kb];
        } else if (AF32) {
            if (ar < M) {
                f0 = *(const float4*)&Af[(size_t)ar * K + kb];
                f1 = *(const float4*)&Af[(size_t)ar * K + kb + 4];
            } else { f0 = make_float4(0, 0, 0, 0); f1 = f0; }
        } else {
            if (ar < M) a = *(const uint4*)&Abf[(size_t)ar * K + kb];
            else a = make_uint4(0, 0, 0, 0);
        }
    };
    auto stage = [&](int k0, int buf, uint4 a, uint4 q, float4 f0, float4 f1) {
        int kb = k0 + skq * 8;
        float v[8];
        if (GATHER) {
            float pa[8], pq[8];
            up8(a, pa); up8(q, pq);
            float4 b0 = *(const float4*)&sBi[kb];
            float4 b1 = *(const float4*)&sBi[kb + 4];
            float bb[8] = {b0.x, b0.y, b0.z, b0.w, b1.x, b1.y, b1.z, b1.w};
            #pragma unroll
            for (int i = 0; i < 8; i++) v[i] = pa[i] + pq[i] + bb[i];
        } else if (AF32) {
            v[0] = f0.x; v[1] = f0.y; v[2] = f0.z; v[3] = f0.w;
            v[4] = f1.x; v[5] = f1.y; v[6] = f1.z; v[7] = f1.w;
        } else {
            up8(a, v);
        }
        if (NORMRELU) {
            float4 a0 = *(const float4*)&sAl[kb];
            float4 a1 = *(const float4*)&sAl[kb + 4];
            float4 e0 = *(const float4*)&sBe[kb];
            float4 e1 = *(const float4*)&sBe[kb + 4];
            float al[8] = {a0.x, a0.y, a0.z, a0.w, a1.x, a1.y, a1.z, a1.w};
            float be[8] = {e0.x, e0.y, e0.z, e0.w, e1.x, e1.y, e1.z, e1.w};
            #pragma unroll
            for (int i = 0; i < 8; i++) v[i] = fmaxf(fmaf(al[i], v[i], be[i]), 0.f);
        }
        if (ROWSC) {
            #pragma unroll
            for (int i = 0; i < 8; i++) v[i] *= rs;
        }
        *(uint4*)&At[buf][srow][skq * 8] = pk8(v);
    };

    loadRaw(0, rA, rQ, fA0, fA1);
    bf16x8 bcur[NF];
    #pragma unroll
    for (int cf = 0; cf < NF; cf++) bcur[cf] = *(const bf16x8*)(bp[cf] + 0);
    __syncthreads();  // tables ready
    stage(0, 0, rA, rQ, fA0, fA1);
    __syncthreads();  // At[0] ready

    int buf = 0;
    for (int k0 = 0; k0 < K; k0 += 32) {
        int nxt = k0 + 32;
        uint4 nA, nQ;
        float4 nf0, nf1;
        bf16x8 bnxt[NF];
        if (nxt < K) {
            loadRaw(nxt, nA, nQ, nf0, nf1);
            #pragma unroll
            for (int cf = 0; cf < NF; cf++) bnxt[cf] = *(const bf16x8*)(bp[cf] + nxt);
        }
        bf16x8 af[4];
        #pragma unroll
        for (int rf = 0; rf < 4; rf++)
            af[rf] = *(const bf16x8*)&At[buf][16 * rf + l15][lq * 8];
        #pragma unroll
        for (int rf = 0; rf < 4; rf++)
            #pragma unroll
            for (int cf = 0; cf < NF; cf++)
                acc[rf][cf] = __builtin_amdgcn_mfma_f32_16x16x32_bf16(
                    af[rf], bcur[cf], acc[rf][cf], 0, 0, 0);
        if (nxt < K) {
            stage(nxt, buf ^ 1, nA, nQ, nf0, nf1);
            __syncthreads();
            buf ^= 1;
            #pragma unroll
            for (int cf = 0; cf < NF; cf++) bcur[cf] = bnxt[cf];
        }
    }

    // ---------------- epilogue ----------------
    int cA[NF];
    float bO[NF], aO[NF], bOo[NF];
    #pragma unroll
    for (int cf = 0; cf < NF; cf++) {
        cA[cf] = n0 + wave * WNC + 16 * cf + l15;
        bO[cf] = (biasOut != nullptr) ? biasOut[cA[cf]] : 0.f;
        if (SCAT) { aO[cf] = alphaO[cA[cf]]; bOo[cf] = betaO[cA[cf]]; }
    }
    float ps[NF], pq[NF];
    #pragma unroll
    for (int cf = 0; cf < NF; cf++) { ps[cf] = 0.f; pq[cf] = 0.f; }
    #pragma unroll
    for (int rf = 0; rf < 4; rf++) {
        int rb = r0 + 16 * rf + lq * 4;
        int dd[4];
        if (SCAT) {
            #pragma unroll
            for (int jj = 0; jj < 4; jj++) dd[jj] = gdst[rb + jj];
        }
        #pragma unroll
        for (int cf = 0; cf < NF; cf++) {
            #pragma unroll
            for (int jj = 0; jj < 4; jj++) {
                float o = acc[rf][cf][jj] + bO[cf];
                if (STATS) { ps[cf] += o; pq[cf] += o * o; }
                if (STORE) {
                    int r = rb + jj;
                    if (r < M) Cmat[(size_t)r * N + cA[cf]] = f2bf(o);
                }
                if (SCAT) {
                    float h = fmaxf(fmaf(aO[cf], o, bOo[cf]), 0.f);
                    atomicAdd(&hsum[(size_t)dd[jj] * N + cA[cf]], h);
                }
            }
        }
    }
    if (STATS) {
        #pragma unroll
        for (int cf = 0; cf < NF; cf++) {
            float s = ps[cf], q = pq[cf];
            s += __shfl_xor(s, 16); s += __shfl_xor(s, 32);
            q += __shfl_xor(q, 16); q += __shfl_xor(q, 32);
            if (lq == 0) {
                atomicAdd(&sS[cA[cf] - n0], s);
                atomicAdd(&sQ[cA[cf] - n0], q);
            }
        }
        __syncthreads();
        if (t < BN) {
            atomicAdd(&ssum[n0 + t], sS[t]);
            atomicAdd(&ssq[n0 + t], sQ[t]);
        }
    }
}

// ---------------- norm+relu a bf16 Y, scatter-add — COALESCED atomics ----------------
// thread t owns channel c = t % C: a wave's atomics hit consecutive words.
template<int C>
__global__ void aggregate_kernel(const unsigned short* __restrict__ Y, const int* __restrict__ dst,
                                 const float* __restrict__ alpha, const float* __restrict__ beta,
                                 float* __restrict__ hsum) {
    constexpr int EPB = 256 / C;
    int c = threadIdx.x % C;
    int sub = threadIdx.x / C;
    float al = alpha[c], be = beta[c];
    for (int e = blockIdx.x * EPB + sub; e < NE; e += gridDim.x * EPB) {
        float v = fmaxf(fmaf(al, bf2f(Y[(size_t)e * C + c]), be), 0.f);
        atomicAdd(&hsum[(size_t)dst[e] * C + c], v);
    }
}

// ---------------- conv3: fused gather+norm+relu+scatter (C=256) — COALESCED atomics ------
__global__ void aggregate_fg_kernel(const unsigned short* __restrict__ RQ,
                                    const int* __restrict__ src, const int* __restrict__ dst,
                                    const float* __restrict__ bias, const float* __restrict__ alpha,
                                    const float* __restrict__ beta, float* __restrict__ hsum) {
    int c = threadIdx.x;  // 256
    float b = bias[c], al = alpha[c], be = beta[c];
    for (int e = blockIdx.x; e < NE; e += gridDim.x) {
        int d = dst[e], s = src[e];
        float v = (bf2f(RQ[(size_t)d * 512 + c]) + bf2f(RQ[(size_t)s * 512 + 256 + c])) + b;
        float h = fmaxf(fmaf(al, v, be), 0.f);
        atomicAdd(&hsum[(size_t)d * 256 + c], h);
    }
}

// ---------------- graph mean pool: contiguous chunks, run-local accumulation ----------------
__global__ void pool_kernel(const float* __restrict__ h3sum, const float* __restrict__ invdeg,
                            const int* __restrict__ batch, float* __restrict__ gsum,
                            int* __restrict__ gcnt) {
    int chunk = (NN + gridDim.x - 1) / gridDim.x;
    int nbeg = blockIdx.x * chunk;
    int nend = min(nbeg + chunk, NN);
    if (nbeg >= nend) return;
    int t = threadIdx.x;  // 256 = channel
    int curg = batch[nbeg];
    float acc = 0.f;
    int cnt = 0;
    for (int n = nbeg; n < nend; n++) {
        int g = batch[n];
        if (g != curg) {
            atomicAdd(&gsum[(size_t)curg * 256 + t], acc);
            if (t == 0) atomicAdd(&gcnt[curg], cnt);
            curg = g; acc = 0.f; cnt = 0;
        }
        acc += h3sum[(size_t)n * 256 + t] * invdeg[n];
        cnt++;
    }
    atomicAdd(&gsum[(size_t)curg * 256 + t], acc);
    if (t == 0) atomicAdd(&gcnt[curg], cnt);
}

// ---------------- final graph MLP ----------------
__global__ void mlp_kernel(const float* __restrict__ gsum, const int* __restrict__ gcnt,
                           const float* __restrict__ W1, const float* __restrict__ b1,
                           const float* __restrict__ W2, const float* __restrict__ b2,
                           float* __restrict__ out) {
    int g = blockIdx.x;
    int t = threadIdx.x;  // 256
    __shared__ float grow[256];
    __shared__ float r0s[256], r1s[256];
    int cnt = gcnt[g];
    float inv = 1.0f / (float)(cnt > 0 ? cnt : 1);
    grow[t] = gsum[(size_t)g * 256 + t] * inv;
    __syncthreads();
    float acc = b1[t];
    for (int k = 0; k < 256; k++) acc = fmaf(grow[k], W1[k * 256 + t], acc);
    float h = fmaxf(acc, 0.f);
    r0s[t] = h * W2[t * 2 + 0];
    r1s[t] = h * W2[t * 2 + 1];
    __syncthreads();
    for (int s = 128; s > 0; s >>= 1) {
        if (t < s) { r0s[t] += r0s[t + s]; r1s[t] += r1s[t + s]; }
        __syncthreads();
    }
    if (t == 0) {
        out[g * 2 + 0] = r0s[0] + b2[0];
        out[g * 2 + 1] = r1s[0] + b2[1];
    }
}

extern "C" void kernel_launch(void* const* d_in, const int* in_sizes, int n_in,
                              void* d_out, int out_size, void* d_ws, size_t ws_size,
                              hipStream_t stream) {
    const float* x      = (const float*)d_in[0];
    const int*   ei     = (const int*)d_in[1];
    const int*   src    = ei;
    const int*   dstp   = ei + NE;
    const int*   batch  = (const int*)d_in[2];
    const float* c1_w1  = (const float*)d_in[3];
    const float* c1_b1  = (const float*)d_in[4];
    const float* c1_gn1 = (const float*)d_in[5];
    const float* c1_w2  = (const float*)d_in[6];
    const float* c1_b2  = (const float*)d_in[7];
    const float* c1_gn2 = (const float*)d_in[8];
    const float* c1_w3  = (const float*)d_in[9];
    const float* c1_b3  = (const float*)d_in[10];
    const float* c1_gn3 = (const float*)d_in[11];
    const float* c2_w1  = (const float*)d_in[12];
    const float* c2_b1  = (const float*)d_in[13];
    const float* c2_gn1 = (const float*)d_in[14];
    const float* c2_w2  = (const float*)d_in[15];
    const float* c2_b2  = (const float*)d_in[16];
    const float* c2_gn2 = (const float*)d_in[17];
    const float* c3_w1  = (const float*)d_in[18];
    const float* c3_b1  = (const float*)d_in[19];
    const float* c3_gn1 = (const float*)d_in[20];
    const float* lin_w1 = (const float*)d_in[21];
    const float* lin_b1 = (const float*)d_in[22];
    const float* lin_w2 = (const float*)d_in[23];
    const float* lin_b2 = (const float*)d_in[24];
    float* out = (float*)d_out;

    // ======== workspace: ping-pong regions RA / RB (102.4 MB each) + tail ========
    //   RA: RQ1[NN,256]bf16 -> Y1c[NE,128]bf16 -> RQ2[NN,512]bf16 -> RQ3[NN,512]bf16
    //   RB: Y1b[NE,128]bf16 -> h1sum[NN,128]f32 -> h2sum[NN,256]f32 -> h3sum[NN,256]f32
    constexpr size_t REG_BYTES = (size_t)NE * 128 * 2;  // 102,400,000
    constexpr size_t NEED = 2 * REG_BYTES + 4 * 1024 * 1024;

    if (ws_size < NEED) {
        diag_kernel<<<(out_size + 255) / 256, 256, 0, stream>>>(
            out, out_size, (float)(ws_size >> 20));
        return;
    }

    char* base = (char*)d_ws;
    unsigned short* RA = (unsigned short*)base;
    unsigned short* RB = (unsigned short*)(base + REG_BYTES);
    float* h1sum = (float*)RB;
    float* h2sum = (float*)RB;
    float* h3sum = (float*)RB;
    char* p = base + 2 * REG_BYTES;
    auto alloc = [&](size_t bytes) -> void* {
        void* r = (void*)p;
        p += (bytes + 255) & ~(size_t)255;
        return r;
    };
    unsigned short* c1w2t = (unsigned short*)alloc((size_t)128 * 128 * 2);
    unsigned short* c1w3t = (unsigned short*)alloc((size_t)128 * 128 * 2);
    unsigned short* c2w2t = (unsigned short*)alloc((size_t)256 * 256 * 2);
    unsigned short* Wpt   = (unsigned short*)alloc((size_t)512 * 256 * 2);
    int*   deg    = (int*)alloc((size_t)NN * 4);
    float* invdeg = (float*)alloc((size_t)NN * 4);
    float* ssum   = (float*)alloc(256 * 4);
    float* ssq    = (float*)alloc(256 * 4);
    float* al0    = (float*)alloc(256 * 4);
    float* be0    = (float*)alloc(256 * 4);
    float* al1    = (float*)alloc(256 * 4);
    float* be1    = (float*)alloc(256 * 4);
    float* gsum   = (float*)alloc((size_t)NG * 256 * 4);
    int*   gcnt   = (int*)alloc((size_t)NG * 4);

    const float invE = 1.0f / (float)NE;
    const int MT_E = NE / 64;
    const int MT_N = (NN + 63) / 64;

    hipMemsetAsync(deg, 0, (size_t)NN * 4, stream);
    hipMemsetAsync(gsum, 0, (size_t)NG * 256 * 4, stream);
    hipMemsetAsync(gcnt, 0, (size_t)NG * 4, stream);

    deg_kernel<<<(NE + 255) / 256, 256, 0, stream>>>(dstp, deg);
    invdeg_kernel<<<(NN + 255) / 256, 256, 0, stream>>>(deg, invdeg);

    wtrans_kernel<<<(128 * 128 + 255) / 256, 256, 0, stream>>>(c1_w2, c1w2t, 128, 128);
    wtrans_kernel<<<(128 * 128 + 255) / 256, 256, 0, stream>>>(c1_w3, c1w3t, 128, 128);
    wtrans_kernel<<<(256 * 256 + 255) / 256, 256, 0, stream>>>(c2_w2, c2w2t, 256, 256);

    // ================= conv1 =================
    conv1_node_kernel<<<2048, 256, 0, stream>>>(x, c1_w1, RA);
    hipMemsetAsync(ssum, 0, 256 * 4, stream);
    hipMemsetAsync(ssq, 0, 256 * 4, stream);
    gstats_kernel<128><<<2048, 256, 0, stream>>>(RA, src, dstp, c1_b1, ssum, ssq);
    finalize_kernel<<<1, 256, 0, stream>>>(ssum, ssq, c1_gn1, 128, invE, al0, be0);

    hipMemsetAsync(ssum, 0, 256 * 4, stream);
    hipMemsetAsync(ssq, 0, 256 * 4, stream);
    mgemm_kernel<128, true, true, false, true, true, false, false>
        <<<dim3(1, MT_E), 256, 0, stream>>>(RA, src, dstp, c1_b1, c1w2t, al0, be0,
                                            nullptr, c1_b2, RB, NE, 128, 128,
                                            ssum, ssq, nullptr, nullptr, nullptr);
    finalize_kernel<<<1, 256, 0, stream>>>(ssum, ssq, c1_gn2, 128, invE, al0, be0);

    hipMemsetAsync(ssum, 0, 256 * 4, stream);
    hipMemsetAsync(ssq, 0, 256 * 4, stream);
    mgemm_kernel<128, false, true, false, true, true, false, false>
        <<<dim3(1, MT_E), 256, 0, stream>>>(RB, nullptr, nullptr, nullptr, c1w3t, al0, be0,
                                            nullptr, c1_b3, RA, NE, 128, 128,
                                            ssum, ssq, nullptr, nullptr, nullptr);
    finalize_kernel<<<1, 256, 0, stream>>>(ssum, ssq, c1_gn3, 128, invE, al0, be0);

    hipMemsetAsync(h1sum, 0, (size_t)NN * 128 * 4, stream);
    aggregate_kernel<128><<<2048, 256, 0, stream>>>(RA, dstp, al0, be0, h1sum);

    // ================= conv2 =================
    wprime_t_kernel<<<(512 * 128 + 255) / 256, 256, 0, stream>>>(c2_w1, Wpt, 128, 256);
    mgemm_kernel<256, false, false, true, false, true, false, true>
        <<<dim3(2, MT_N), 256, 0, stream>>>(h1sum, nullptr, nullptr, nullptr, Wpt,
                                            nullptr, nullptr, invdeg, nullptr, RA,
                                            NN, 128, 512, nullptr, nullptr,
                                            nullptr, nullptr, nullptr);
    hipMemsetAsync(ssum, 0, 256 * 4, stream);
    hipMemsetAsync(ssq, 0, 256 * 4, stream);
    gstats_kernel<256><<<2048, 256, 0, stream>>>(RA, src, dstp, c2_b1, ssum, ssq);
    finalize_kernel<<<1, 256, 0, stream>>>(ssum, ssq, c2_gn1, 256, invE, al0, be0);

    hipMemsetAsync(ssum, 0, 256 * 4, stream);
    hipMemsetAsync(ssq, 0, 256 * 4, stream);
    mgemm_kernel<256, true, true, false, true, false, false, false>
        <<<dim3(1, MT_E), 256, 0, stream>>>(RA, src, dstp, c2_b1, c2w2t, al0, be0,
                                            nullptr, c2_b2, nullptr, NE, 256, 256,
                                            ssum, ssq, nullptr, nullptr, nullptr);
    finalize_kernel<<<1, 256, 0, stream>>>(ssum, ssq, c2_gn2, 256, invE, al1, be1);

    hipMemsetAsync(h2sum, 0, (size_t)NN * 256 * 4, stream);
    mgemm_kernel<256, true, true, false, false, false, true, false>
        <<<dim3(1, MT_E), 256, 0, stream>>>(RA, src, dstp, c2_b1, c2w2t, al0, be0,
                                            nullptr, c2_b2, nullptr, NE, 256, 256,
                                            nullptr, nullptr, al1, be1, h2sum);

    // ================= conv3 =================
    wprime_t_kernel<<<(512 * 256 + 255) / 256, 256, 0, stream>>>(c3_w1, Wpt, 256, 256);
    mgemm_kernel<256, false, false, true, false, true, false, true>
        <<<dim3(2, MT_N), 256, 0, stream>>>(h2sum, nullptr, nullptr, nullptr, Wpt,
                                            nullptr, nullptr, invdeg, nullptr, RA,
                                            NN, 256, 512, nullptr, nullptr,
                                            nullptr, nullptr, nullptr);
    hipMemsetAsync(ssum, 0, 256 * 4, stream);
    hipMemsetAsync(ssq, 0, 256 * 4, stream);
    gstats_kernel<256><<<2048, 256, 0, stream>>>(RA, src, dstp, c3_b1, ssum, ssq);
    finalize_kernel<<<1, 256, 0, stream>>>(ssum, ssq, c3_gn1, 256, invE, al0, be0);

    hipMemsetAsync(h3sum, 0, (size_t)NN * 256 * 4, stream);
    aggregate_fg_kernel<<<2048, 256, 0, stream>>>(RA, src, dstp, c3_b1, al0, be0, h3sum);

    // ================= pool + MLP =================
    pool_kernel<<<512, 256, 0, stream>>>(h3sum, invdeg, batch, gsum, gcnt);
    mlp_kernel<<<NG, 256, 0, stream>>>(gsum, gcnt, lin_w1, lin_b1, lin_w2, lin_b2, out);
}

// Round 8
// 2209.228 us; speedup vs baseline: 2.7039x; 1.0346x over previous
//
#include <hip/hip_runtime.h>
#include <hip/hip_bf16.h>

#define NN 100000
#define NE 400000
#define NG 1000

typedef __attribute__((ext_vector_type(8))) short bf16x8;
typedef __attribute__((ext_vector_type(4))) float f32x4;

// ---------------- bf16 <-> f32 helpers (bit-level, RNE) ----------------
__device__ __forceinline__ float bf2f(unsigned short h) {
    return __uint_as_float((unsigned)h << 16);
}
__device__ __forceinline__ unsigned short f2bf(float f) {
    unsigned u = __float_as_uint(f);
    return (unsigned short)((u + 0x7FFFu + ((u >> 16) & 1u)) >> 16);
}
__device__ __forceinline__ void up8(uint4 u, float v[8]) {
    v[0] = bf2f((unsigned short)u.x); v[1] = bf2f((unsigned short)(u.x >> 16));
    v[2] = bf2f((unsigned short)u.y); v[3] = bf2f((unsigned short)(u.y >> 16));
    v[4] = bf2f((unsigned short)u.z); v[5] = bf2f((unsigned short)(u.z >> 16));
    v[6] = bf2f((unsigned short)u.w); v[7] = bf2f((unsigned short)(u.w >> 16));
}
__device__ __forceinline__ uint4 pk8(const float v[8]) {
    uint4 r;
    r.x = (uint)f2bf(v[0]) | ((uint)f2bf(v[1]) << 16);
    r.y = (uint)f2bf(v[2]) | ((uint)f2bf(v[3]) << 16);
    r.z = (uint)f2bf(v[4]) | ((uint)f2bf(v[5]) << 16);
    r.w = (uint)f2bf(v[6]) | ((uint)f2bf(v[7]) << 16);
    return r;
}

// ---------------- diagnostic fallback ----------------
__global__ void diag_kernel(float* __restrict__ out, int n, float val) {
    int i = blockIdx.x * 256 + threadIdx.x;
    if (i < n) out[i] = val;
}

// ---------------- degree / invdeg ----------------
__global__ void deg_kernel(const int* __restrict__ dst, int* __restrict__ deg) {
    int e = blockIdx.x * 256 + threadIdx.x;
    if (e < NE) atomicAdd(&deg[dst[e]], 1);
}

__global__ void invdeg_kernel(const int* __restrict__ deg, float* __restrict__ invdeg) {
    int n = blockIdx.x * 256 + threadIdx.x;
    if (n < NN) invdeg[n] = 1.0f / (float)(deg[n] > 0 ? deg[n] : 1);
}

// ---------------- conv1 node-level first linear (K=5), bf16 out ----------------
__global__ void conv1_node_kernel(const float* __restrict__ x, const float* __restrict__ W,
                                  unsigned short* __restrict__ RQ) {
    __shared__ float Ws[1280];  // [10][128]
    for (int i = threadIdx.x; i < 1280; i += 256) Ws[i] = W[i];
    __syncthreads();
    int c = threadIdx.x & 127;
    int which = threadIdx.x >> 7;
    for (int n = blockIdx.x; n < NN; n += gridDim.x) {
        float acc = 0.f;
        #pragma unroll
        for (int r = 0; r < 5; r++) {
            float xv = x[n * 5 + r];
            float bot = Ws[(5 + r) * 128 + c];
            float w = which ? bot : (Ws[r * 128 + c] - bot);
            acc = fmaf(xv, w, acc);
        }
        RQ[(size_t)n * 256 + threadIdx.x] = f2bf(acc);
    }
}

// ---------------- weight transpose+convert: Wt[N][K] bf16 from W[K][N] f32 ----------------
__global__ void wtrans_kernel(const float* __restrict__ W, unsigned short* __restrict__ Wt,
                              int K, int N) {
    int idx = blockIdx.x * 256 + threadIdx.x;
    if (idx >= K * N) return;
    int c = idx / K, k = idx - c * K;
    Wt[(size_t)c * K + k] = f2bf(W[(size_t)k * N + c]);
}

// ---------------- wprime transposed bf16: Wpt[2C][K] from W[2K][C] ----------------
__global__ void wprime_t_kernel(const float* __restrict__ W, unsigned short* __restrict__ Wpt,
                                int K, int C) {
    int idx = blockIdx.x * 256 + threadIdx.x;
    if (idx >= 2 * C * K) return;
    int n = idx / K, k = idx - n * K;
    float v;
    if (n < C) v = W[(size_t)k * C + n] - W[(size_t)(K + k) * C + n];
    else       v = W[(size_t)(K + k) * C + (n - C)];
    Wpt[(size_t)n * K + k] = f2bf(v);
}

// ---------------- gather-stats (vectorized loads, NO store, LDS reduce) ----------------
template<int C>
__global__ void gstats_kernel(const unsigned short* __restrict__ RQ, const int* __restrict__ src,
                              const int* __restrict__ dst, const float* __restrict__ bias,
                              float* __restrict__ ssum, float* __restrict__ ssq) {
    constexpr int LPE = C / 8;        // lanes per edge
    constexpr int EPB = 256 / LPE;    // edges per block-iter
    const int t = threadIdx.x;
    const int le = t % LPE, sub = t / LPE;
    const int c0 = le * 8;
    float4 b0 = *(const float4*)&bias[c0];
    float4 b1 = *(const float4*)&bias[c0 + 4];
    float bb[8] = {b0.x, b0.y, b0.z, b0.w, b1.x, b1.y, b1.z, b1.w};
    float ls[8], lq[8];
    #pragma unroll
    for (int i = 0; i < 8; i++) { ls[i] = 0.f; lq[i] = 0.f; }
    for (int e = blockIdx.x * EPB + sub; e < NE; e += gridDim.x * EPB) {
        int d = dst[e], s = src[e];
        uint4 rr = *(const uint4*)&RQ[(size_t)d * (2 * C) + c0];
        uint4 qq = *(const uint4*)&RQ[(size_t)s * (2 * C) + C + c0];
        float pr[8], pq[8];
        up8(rr, pr); up8(qq, pq);
        #pragma unroll
        for (int i = 0; i < 8; i++) {
            float v = pr[i] + pq[i] + bb[i];
            ls[i] += v; lq[i] += v * v;
        }
    }
    __shared__ float red[2][256][8];
    #pragma unroll
    for (int i = 0; i < 8; i++) { red[0][t][i] = ls[i]; red[1][t][i] = lq[i]; }
    __syncthreads();
    if (t < C) {
        int le2 = t >> 3, ch = t & 7;
        float s = 0.f, q = 0.f;
        #pragma unroll
        for (int g = 0; g < EPB; g++) {
            s += red[0][g * LPE + le2][ch];
            q += red[1][g * LPE + le2][ch];
        }
        atomicAdd(&ssum[t], s);
        atomicAdd(&ssq[t], q);
    }
}

// ---------------- GraphNorm stats -> per-channel affine ----------------
__global__ void finalize_kernel(const float* __restrict__ ssum, const float* __restrict__ ssq,
                                const float* __restrict__ gn, int C, float invM,
                                float* __restrict__ alpha, float* __restrict__ beta) {
    int c = threadIdx.x;
    if (c >= C) return;
    float g = gn[c], b = gn[C + c], ms = gn[2 * C + c];
    float m = ssum[c] * invM;
    float var = ssq[c] * invM - m * m * ms * (2.f - ms);
    float inv = rsqrtf(var + 1e-5f);
    alpha[c] = g * inv;
    beta[c] = b - g * inv * ms * m;
}

// ================= MFMA GEMM v3: one-shot A staging, barrier-free K-loop =================
// Block: 256 thr (4 waves), tile 64 x BN, K = TK (compile-time). Phase 1 stages the whole
// 64xTK A-tile (gather+bias+norm+relu+rowscale fused) into LDS; ONE barrier; phase 2 is a
// fully-unrolled K-loop of pure {ds_read A-frag, global-load B-frag, MFMA} — no barriers,
// no VALU — letting the compiler pipeline with fine-grained lgkmcnt.
template<int TK, int BN, bool GATHER, bool NORMRELU, bool ROWSC, bool STATS, bool STORE,
         bool SCAT, bool AF32>
__global__ __launch_bounds__(256) void mgemm_kernel(
    const void* __restrict__ Av, const int* __restrict__ gsrc, const int* __restrict__ gdst,
    const float* __restrict__ biasIn, const unsigned short* __restrict__ Wt,
    const float* __restrict__ alpha, const float* __restrict__ beta,
    const float* __restrict__ rowscale, const float* __restrict__ biasOut,
    unsigned short* __restrict__ Cmat, int M, int N,
    float* __restrict__ ssum, float* __restrict__ ssq,
    const float* __restrict__ alphaO, const float* __restrict__ betaO,
    float* __restrict__ hsum) {
    constexpr int WNC = BN / 4;          // cols per wave
    constexpr int NF = WNC / 16;         // col fragments per wave
    constexpr int SPR = TK / 8;          // uint4 slots per A row
    constexpr int ITER = 64 * SPR / 256; // staging iterations
    __shared__ __align__(16) unsigned short At[64][TK + 8];
    __shared__ __align__(16) float sAl[TK], sBe[TK], sBi[TK];
    __shared__ float sS[BN], sQ[BN];
    const int t = threadIdx.x;
    const int wave = t >> 6, lane = t & 63;
    const int l15 = lane & 15, lq = lane >> 4;
    const int r0 = blockIdx.y * 64;
    const int n0 = blockIdx.x * BN;

    if (NORMRELU) for (int i = t; i < TK; i += 256) { sAl[i] = alpha[i]; sBe[i] = beta[i]; }
    if (GATHER)   for (int i = t; i < TK; i += 256) { sBi[i] = biasIn[i]; }
    if (STATS && t < BN) { sS[t] = 0.f; sQ[t] = 0.f; }
    __syncthreads();  // tables ready

    const unsigned short* Abf = (const unsigned short*)Av;
    const float* Af = (const float*)Av;

    // ---------- phase 1: stage whole A tile ----------
    #pragma unroll
    for (int it = 0; it < ITER; it++) {
        int slot = it * 256 + t;
        int row = slot / SPR;
        int c0 = (slot - row * SPR) * 8;
        int ar = r0 + row;
        float v[8];
        if (GATHER) {  // M % 64 == 0 for all GATHER uses
            int gd = gdst[ar], gs = gsrc[ar];
            uint4 pa4 = *(const uint4*)&Abf[(size_t)gd * (2 * TK) + c0];
            uint4 pq4 = *(const uint4*)&Abf[(size_t)gs * (2 * TK) + TK + c0];
            float pa[8], pq[8];
            up8(pa4, pa); up8(pq4, pq);
            #pragma unroll
            for (int i = 0; i < 8; i++) v[i] = pa[i] + pq[i] + sBi[c0 + i];
        } else if (AF32) {
            if (ar < M) {
                float4 f0 = *(const float4*)&Af[(size_t)ar * TK + c0];
                float4 f1 = *(const float4*)&Af[(size_t)ar * TK + c0 + 4];
                v[0] = f0.x; v[1] = f0.y; v[2] = f0.z; v[3] = f0.w;
                v[4] = f1.x; v[5] = f1.y; v[6] = f1.z; v[7] = f1.w;
            } else {
                #pragma unroll
                for (int i = 0; i < 8; i++) v[i] = 0.f;
            }
        } else {
            if (ar < M) {
                uint4 a4 = *(const uint4*)&Abf[(size_t)ar * TK + c0];
                up8(a4, v);
            } else {
                #pragma unroll
                for (int i = 0; i < 8; i++) v[i] = 0.f;
            }
        }
        if (NORMRELU) {
            #pragma unroll
            for (int i = 0; i < 8; i++)
                v[i] = fmaxf(fmaf(sAl[c0 + i], v[i], sBe[c0 + i]), 0.f);
        }
        if (ROWSC) {
            float rs = (ar < M) ? rowscale[ar] : 0.f;
            #pragma unroll
            for (int i = 0; i < 8; i++) v[i] *= rs;
        }
        *(uint4*)&At[row][c0] = pk8(v);
    }
    __syncthreads();  // A-tile ready; no more barriers

    // ---------- phase 2: barrier-free MFMA loop ----------
    const unsigned short* bp[NF];
    #pragma unroll
    for (int cf = 0; cf < NF; cf++)
        bp[cf] = &Wt[(size_t)(n0 + wave * WNC + 16 * cf + l15) * TK + lq * 8];

    f32x4 acc[4][NF];
    #pragma unroll
    for (int i = 0; i < 4; i++)
        #pragma unroll
        for (int j = 0; j < NF; j++) acc[i][j] = {0.f, 0.f, 0.f, 0.f};

    #pragma unroll
    for (int k0 = 0; k0 < TK; k0 += 32) {
        bf16x8 af[4];
        #pragma unroll
        for (int rf = 0; rf < 4; rf++)
            af[rf] = *(const bf16x8*)&At[16 * rf + l15][k0 + lq * 8];
        bf16x8 bfr[NF];
        #pragma unroll
        for (int cf = 0; cf < NF; cf++)
            bfr[cf] = *(const bf16x8*)(bp[cf] + k0);
        #pragma unroll
        for (int rf = 0; rf < 4; rf++)
            #pragma unroll
            for (int cf = 0; cf < NF; cf++)
                acc[rf][cf] = __builtin_amdgcn_mfma_f32_16x16x32_bf16(
                    af[rf], bfr[cf], acc[rf][cf], 0, 0, 0);
    }

    // ---------------- epilogue ----------------
    int cA[NF];
    float bO[NF], aO[NF], bOo[NF];
    #pragma unroll
    for (int cf = 0; cf < NF; cf++) {
        cA[cf] = n0 + wave * WNC + 16 * cf + l15;
        bO[cf] = (biasOut != nullptr) ? biasOut[cA[cf]] : 0.f;
        if (SCAT) { aO[cf] = alphaO[cA[cf]]; bOo[cf] = betaO[cA[cf]]; }
    }
    float ps[NF], pq[NF];
    #pragma unroll
    for (int cf = 0; cf < NF; cf++) { ps[cf] = 0.f; pq[cf] = 0.f; }
    #pragma unroll
    for (int rf = 0; rf < 4; rf++) {
        int rb = r0 + 16 * rf + lq * 4;
        int dd[4];
        if (SCAT) {
            #pragma unroll
            for (int jj = 0; jj < 4; jj++) dd[jj] = gdst[rb + jj];
        }
        #pragma unroll
        for (int cf = 0; cf < NF; cf++) {
            #pragma unroll
            for (int jj = 0; jj < 4; jj++) {
                float o = acc[rf][cf][jj] + bO[cf];
                if (STATS) { ps[cf] += o; pq[cf] += o * o; }
                if (STORE) {
                    int r = rb + jj;
                    if (r < M) Cmat[(size_t)r * N + cA[cf]] = f2bf(o);
                }
                if (SCAT) {
                    float h = fmaxf(fmaf(aO[cf], o, bOo[cf]), 0.f);
                    atomicAdd(&hsum[(size_t)dd[jj] * N + cA[cf]], h);
                }
            }
        }
    }
    if (STATS) {
        #pragma unroll
        for (int cf = 0; cf < NF; cf++) {
            float s = ps[cf], q = pq[cf];
            s += __shfl_xor(s, 16); s += __shfl_xor(s, 32);
            q += __shfl_xor(q, 16); q += __shfl_xor(q, 32);
            if (lq == 0) {
                atomicAdd(&sS[cA[cf] - n0], s);
                atomicAdd(&sQ[cA[cf] - n0], q);
            }
        }
        __syncthreads();
        if (t < BN) {
            atomicAdd(&ssum[n0 + t], sS[t]);
            atomicAdd(&ssq[n0 + t], sQ[t]);
        }
    }
}

// ---------------- norm+relu a bf16 Y, scatter-add — COALESCED atomics ----------------
template<int C>
__global__ void aggregate_kernel(const unsigned short* __restrict__ Y, const int* __restrict__ dst,
                                 const float* __restrict__ alpha, const float* __restrict__ beta,
                                 float* __restrict__ hsum) {
    constexpr int EPB = 256 / C;
    int c = threadIdx.x % C;
    int sub = threadIdx.x / C;
    float al = alpha[c], be = beta[c];
    for (int e = blockIdx.x * EPB + sub; e < NE; e += gridDim.x * EPB) {
        float v = fmaxf(fmaf(al, bf2f(Y[(size_t)e * C + c]), be), 0.f);
        atomicAdd(&hsum[(size_t)dst[e] * C + c], v);
    }
}

// ---------------- conv3: fused gather+norm+relu+scatter (C=256) — COALESCED atomics ------
__global__ void aggregate_fg_kernel(const unsigned short* __restrict__ RQ,
                                    const int* __restrict__ src, const int* __restrict__ dst,
                                    const float* __restrict__ bias, const float* __restrict__ alpha,
                                    const float* __restrict__ beta, float* __restrict__ hsum) {
    int c = threadIdx.x;  // 256
    float b = bias[c], al = alpha[c], be = beta[c];
    for (int e = blockIdx.x; e < NE; e += gridDim.x) {
        int d = dst[e], s = src[e];
        float v = (bf2f(RQ[(size_t)d * 512 + c]) + bf2f(RQ[(size_t)s * 512 + 256 + c])) + b;
        float h = fmaxf(fmaf(al, v, be), 0.f);
        atomicAdd(&hsum[(size_t)d * 256 + c], h);
    }
}

// ---------------- graph mean pool: contiguous chunks, run-local accumulation ----------------
__global__ void pool_kernel(const float* __restrict__ h3sum, const float* __restrict__ invdeg,
                            const int* __restrict__ batch, float* __restrict__ gsum,
                            int* __restrict__ gcnt) {
    int chunk = (NN + gridDim.x - 1) / gridDim.x;
    int nbeg = blockIdx.x * chunk;
    int nend = min(nbeg + chunk, NN);
    if (nbeg >= nend) return;
    int t = threadIdx.x;  // 256 = channel
    int curg = batch[nbeg];
    float acc = 0.f;
    int cnt = 0;
    for (int n = nbeg; n < nend; n++) {
        int g = batch[n];
        if (g != curg) {
            atomicAdd(&gsum[(size_t)curg * 256 + t], acc);
            if (t == 0) atomicAdd(&gcnt[curg], cnt);
            curg = g; acc = 0.f; cnt = 0;
        }
        acc += h3sum[(size_t)n * 256 + t] * invdeg[n];
        cnt++;
    }
    atomicAdd(&gsum[(size_t)curg * 256 + t], acc);
    if (t == 0) atomicAdd(&gcnt[curg], cnt);
}

// ---------------- final graph MLP ----------------
__global__ void mlp_kernel(const float* __restrict__ gsum, const int* __restrict__ gcnt,
                           const float* __restrict__ W1, const float* __restrict__ b1,
                           const float* __restrict__ W2, const float* __restrict__ b2,
                           float* __restrict__ out) {
    int g = blockIdx.x;
    int t = threadIdx.x;  // 256
    __shared__ float grow[256];
    __shared__ float r0s[256], r1s[256];
    int cnt = gcnt[g];
    float inv = 1.0f / (float)(cnt > 0 ? cnt : 1);
    grow[t] = gsum[(size_t)g * 256 + t] * inv;
    __syncthreads();
    float acc = b1[t];
    for (int k = 0; k < 256; k++) acc = fmaf(grow[k], W1[k * 256 + t], acc);
    float h = fmaxf(acc, 0.f);
    r0s[t] = h * W2[t * 2 + 0];
    r1s[t] = h * W2[t * 2 + 1];
    __syncthreads();
    for (int s = 128; s > 0; s >>= 1) {
        if (t < s) { r0s[t] += r0s[t + s]; r1s[t] += r1s[t + s]; }
        __syncthreads();
    }
    if (t == 0) {
        out[g * 2 + 0] = r0s[0] + b2[0];
        out[g * 2 + 1] = r1s[0] + b2[1];
    }
}

extern "C" void kernel_launch(void* const* d_in, const int* in_sizes, int n_in,
                              void* d_out, int out_size, void* d_ws, size_t ws_size,
                              hipStream_t stream) {
    const float* x      = (const float*)d_in[0];
    const int*   ei     = (const int*)d_in[1];
    const int*   src    = ei;
    const int*   dstp   = ei + NE;
    const int*   batch  = (const int*)d_in[2];
    const float* c1_w1  = (const float*)d_in[3];
    const float* c1_b1  = (const float*)d_in[4];
    const float* c1_gn1 = (const float*)d_in[5];
    const float* c1_w2  = (const float*)d_in[6];
    const float* c1_b2  = (const float*)d_in[7];
    const float* c1_gn2 = (const float*)d_in[8];
    const float* c1_w3  = (const float*)d_in[9];
    const float* c1_b3  = (const float*)d_in[10];
    const float* c1_gn3 = (const float*)d_in[11];
    const float* c2_w1  = (const float*)d_in[12];
    const float* c2_b1  = (const float*)d_in[13];
    const float* c2_gn1 = (const float*)d_in[14];
    const float* c2_w2  = (const float*)d_in[15];
    const float* c2_b2  = (const float*)d_in[16];
    const float* c2_gn2 = (const float*)d_in[17];
    const float* c3_w1  = (const float*)d_in[18];
    const float* c3_b1  = (const float*)d_in[19];
    const float* c3_gn1 = (const float*)d_in[20];
    const float* lin_w1 = (const float*)d_in[21];
    const float* lin_b1 = (const float*)d_in[22];
    const float* lin_w2 = (const float*)d_in[23];
    const float* lin_b2 = (const float*)d_in[24];
    float* out = (float*)d_out;

    // ======== workspace: ping-pong regions RA / RB (102.4 MB each) + tail ========
    //   RA: RQ1[NN,256]bf16 -> Y1c[NE,128]bf16 -> RQ2[NN,512]bf16 -> RQ3[NN,512]bf16
    //   RB: Y1b[NE,128]bf16 -> h1sum[NN,128]f32 -> h2sum[NN,256]f32 -> h3sum[NN,256]f32
    constexpr size_t REG_BYTES = (size_t)NE * 128 * 2;  // 102,400,000
    constexpr size_t NEED = 2 * REG_BYTES + 4 * 1024 * 1024;

    if (ws_size < NEED) {
        diag_kernel<<<(out_size + 255) / 256, 256, 0, stream>>>(
            out, out_size, (float)(ws_size >> 20));
        return;
    }

    char* base = (char*)d_ws;
    unsigned short* RA = (unsigned short*)base;
    unsigned short* RB = (unsigned short*)(base + REG_BYTES);
    float* h1sum = (float*)RB;
    float* h2sum = (float*)RB;
    float* h3sum = (float*)RB;
    char* p = base + 2 * REG_BYTES;
    auto alloc = [&](size_t bytes) -> void* {
        void* r = (void*)p;
        p += (bytes + 255) & ~(size_t)255;
        return r;
    };
    unsigned short* c1w2t = (unsigned short*)alloc((size_t)128 * 128 * 2);
    unsigned short* c1w3t = (unsigned short*)alloc((size_t)128 * 128 * 2);
    unsigned short* c2w2t = (unsigned short*)alloc((size_t)256 * 256 * 2);
    unsigned short* Wpt   = (unsigned short*)alloc((size_t)512 * 256 * 2);
    int*   deg    = (int*)alloc((size_t)NN * 4);
    float* invdeg = (float*)alloc((size_t)NN * 4);
    float* ssum   = (float*)alloc(256 * 4);
    float* ssq    = (float*)alloc(256 * 4);
    float* al0    = (float*)alloc(256 * 4);
    float* be0    = (float*)alloc(256 * 4);
    float* al1    = (float*)alloc(256 * 4);
    float* be1    = (float*)alloc(256 * 4);
    float* gsum   = (float*)alloc((size_t)NG * 256 * 4);
    int*   gcnt   = (int*)alloc((size_t)NG * 4);

    const float invE = 1.0f / (float)NE;
    const int MT_E = NE / 64;
    const int MT_N = (NN + 63) / 64;

    hipMemsetAsync(deg, 0, (size_t)NN * 4, stream);
    hipMemsetAsync(gsum, 0, (size_t)NG * 256 * 4, stream);
    hipMemsetAsync(gcnt, 0, (size_t)NG * 4, stream);

    deg_kernel<<<(NE + 255) / 256, 256, 0, stream>>>(dstp, deg);
    invdeg_kernel<<<(NN + 255) / 256, 256, 0, stream>>>(deg, invdeg);

    wtrans_kernel<<<(128 * 128 + 255) / 256, 256, 0, stream>>>(c1_w2, c1w2t, 128, 128);
    wtrans_kernel<<<(128 * 128 + 255) / 256, 256, 0, stream>>>(c1_w3, c1w3t, 128, 128);
    wtrans_kernel<<<(256 * 256 + 255) / 256, 256, 0, stream>>>(c2_w2, c2w2t, 256, 256);

    // ================= conv1 =================
    conv1_node_kernel<<<2048, 256, 0, stream>>>(x, c1_w1, RA);
    hipMemsetAsync(ssum, 0, 256 * 4, stream);
    hipMemsetAsync(ssq, 0, 256 * 4, stream);
    gstats_kernel<128><<<2048, 256, 0, stream>>>(RA, src, dstp, c1_b1, ssum, ssq);
    finalize_kernel<<<1, 256, 0, stream>>>(ssum, ssq, c1_gn1, 128, invE, al0, be0);

    hipMemsetAsync(ssum, 0, 256 * 4, stream);
    hipMemsetAsync(ssq, 0, 256 * 4, stream);
    mgemm_kernel<128, 128, true, true, false, true, true, false, false>
        <<<dim3(1, MT_E), 256, 0, stream>>>(RA, src, dstp, c1_b1, c1w2t, al0, be0,
                                            nullptr, c1_b2, RB, NE, 128,
                                            ssum, ssq, nullptr, nullptr, nullptr);
    finalize_kernel<<<1, 256, 0, stream>>>(ssum, ssq, c1_gn2, 128, invE, al0, be0);

    hipMemsetAsync(ssum, 0, 256 * 4, stream);
    hipMemsetAsync(ssq, 0, 256 * 4, stream);
    mgemm_kernel<128, 128, false, true, false, true, true, false, false>
        <<<dim3(1, MT_E), 256, 0, stream>>>(RB, nullptr, nullptr, nullptr, c1w3t, al0, be0,
                                            nullptr, c1_b3, RA, NE, 128,
                                            ssum, ssq, nullptr, nullptr, nullptr);
    finalize_kernel<<<1, 256, 0, stream>>>(ssum, ssq, c1_gn3, 128, invE, al0, be0);

    hipMemsetAsync(h1sum, 0, (size_t)NN * 128 * 4, stream);
    aggregate_kernel<128><<<2048, 256, 0, stream>>>(RA, dstp, al0, be0, h1sum);

    // ================= conv2 =================
    wprime_t_kernel<<<(512 * 128 + 255) / 256, 256, 0, stream>>>(c2_w1, Wpt, 128, 256);
    mgemm_kernel<128, 256, false, false, true, false, true, false, true>
        <<<dim3(2, MT_N), 256, 0, stream>>>(h1sum, nullptr, nullptr, nullptr, Wpt,
                                            nullptr, nullptr, invdeg, nullptr, RA,
                                            NN, 512, nullptr, nullptr,
                                            nullptr, nullptr, nullptr);
    hipMemsetAsync(ssum, 0, 256 * 4, stream);
    hipMemsetAsync(ssq, 0, 256 * 4, stream);
    gstats_kernel<256><<<2048, 256, 0, stream>>>(RA, src, dstp, c2_b1, ssum, ssq);
    finalize_kernel<<<1, 256, 0, stream>>>(ssum, ssq, c2_gn1, 256, invE, al0, be0);

    hipMemsetAsync(ssum, 0, 256 * 4, stream);
    hipMemsetAsync(ssq, 0, 256 * 4, stream);
    mgemm_kernel<256, 256, true, true, false, true, false, false, false>
        <<<dim3(1, MT_E), 256, 0, stream>>>(RA, src, dstp, c2_b1, c2w2t, al0, be0,
                                            nullptr, c2_b2, nullptr, NE, 256,
                                            ssum, ssq, nullptr, nullptr, nullptr);
    finalize_kernel<<<1, 256, 0, stream>>>(ssum, ssq, c2_gn2, 256, invE, al1, be1);

    hipMemsetAsync(h2sum, 0, (size_t)NN * 256 * 4, stream);
    mgemm_kernel<256, 256, true, true, false, false, false, true, false>
        <<<dim3(1, MT_E), 256, 0, stream>>>(RA, src, dstp, c2_b1, c2w2t, al0, be0,
                                            nullptr, c2_b2, nullptr, NE, 256,
                                            nullptr, nullptr, al1, be1, h2sum);

    // ================= conv3 =================
    wprime_t_kernel<<<(512 * 256 + 255) / 256, 256, 0, stream>>>(c3_w1, Wpt, 256, 256);
    mgemm_kernel<256, 256, false, false, true, false, true, false, true>
        <<<dim3(2, MT_N), 256, 0, stream>>>(h2sum, nullptr, nullptr, nullptr, Wpt,
                                            nullptr, nullptr, invdeg, nullptr, RA,
                                            NN, 512, nullptr, nullptr,
                                            nullptr, nullptr, nullptr);
    hipMemsetAsync(ssum, 0, 256 * 4, stream);
    hipMemsetAsync(ssq, 0, 256 * 4, stream);
    gstats_kernel<256><<<2048, 256, 0, stream>>>(RA, src, dstp, c3_b1, ssum, ssq);
    finalize_kernel<<<1, 256, 0, stream>>>(ssum, ssq, c3_gn1, 256, invE, al0, be0);

    hipMemsetAsync(h3sum, 0, (size_t)NN * 256 * 4, stream);
    aggregate_fg_kernel<<<2048, 256, 0, stream>>>(RA, src, dstp, c3_b1, al0, be0, h3sum);

    // ================= pool + MLP =================
    pool_kernel<<<512, 256, 0, stream>>>(h3sum, invdeg, batch, gsum, gcnt);
    mlp_kernel<<<NG, 256, 0, stream>>>(gsum, gcnt, lin_w1, lin_b1, lin_w2, lin_b2, out);
}